// Round 3
// baseline (3901.233 us; speedup 1.0000x reference)
//
#include <hip/hip_runtime.h>
#include <cstdint>

using u16 = unsigned short;
using u32 = uint32_t;

typedef __bf16 bf16x8 __attribute__((ext_vector_type(8)));
typedef float  f32x4  __attribute__((ext_vector_type(4)));

typedef const __attribute__((address_space(1))) void GV;
typedef __attribute__((address_space(3))) void LV;

static __device__ __forceinline__ void gl_lds16(const u16* g, u16* l) {
  __builtin_amdgcn_global_load_lds((GV*)g, (LV*)l, 16, 0, 0);
}

// ---------------- numeric helpers ----------------
static __device__ __forceinline__ u16 f2bf(float x) {
  u32 u = __float_as_uint(x);
  u32 r = (u + 0x7FFFu + ((u >> 16) & 1u)) >> 16;   // RNE
  return (u16)r;
}

static __device__ __forceinline__ u32 rotl32(u32 v, int s) {
  return (v << s) | (v >> (32 - s));
}

// JAX threefry2x32 (20 rounds)
static __device__ __forceinline__ void threefry2x32(u32 k0, u32 k1, u32 x0, u32 x1,
                                                    u32& o0, u32& o1) {
  u32 k2 = k0 ^ k1 ^ 0x1BD11BDAu;
  x0 += k0; x1 += k1;
  x0 += x1; x1 = rotl32(x1, 13); x1 ^= x0;
  x0 += x1; x1 = rotl32(x1, 15); x1 ^= x0;
  x0 += x1; x1 = rotl32(x1, 26); x1 ^= x0;
  x0 += x1; x1 = rotl32(x1, 6);  x1 ^= x0;
  x0 += k1; x1 += k2 + 1u;
  x0 += x1; x1 = rotl32(x1, 17); x1 ^= x0;
  x0 += x1; x1 = rotl32(x1, 29); x1 ^= x0;
  x0 += x1; x1 = rotl32(x1, 16); x1 ^= x0;
  x0 += x1; x1 = rotl32(x1, 24); x1 ^= x0;
  x0 += k2; x1 += k0 + 2u;
  x0 += x1; x1 = rotl32(x1, 13); x1 ^= x0;
  x0 += x1; x1 = rotl32(x1, 15); x1 ^= x0;
  x0 += x1; x1 = rotl32(x1, 26); x1 ^= x0;
  x0 += x1; x1 = rotl32(x1, 6);  x1 ^= x0;
  x0 += k0; x1 += k1 + 3u;
  x0 += x1; x1 = rotl32(x1, 17); x1 ^= x0;
  x0 += x1; x1 = rotl32(x1, 29); x1 ^= x0;
  x0 += x1; x1 = rotl32(x1, 16); x1 ^= x0;
  x0 += x1; x1 = rotl32(x1, 24); x1 ^= x0;
  x0 += k1; x1 += k2 + 4u;
  x0 += x1; x1 = rotl32(x1, 13); x1 ^= x0;
  x0 += x1; x1 = rotl32(x1, 15); x1 ^= x0;
  x0 += x1; x1 = rotl32(x1, 26); x1 ^= x0;
  x0 += x1; x1 = rotl32(x1, 6);  x1 ^= x0;
  x0 += k2; x1 += k0 + 5u;
  o0 = x0; o1 = x1;
}

// bits -> N(0,1) exactly like jax.random.normal(f32)
static __device__ __forceinline__ float bits_to_normal(u32 bits) {
  const float lo = __uint_as_float(0xBF7FFFFFu);
  float f = __uint_as_float((bits >> 9) | 0x3F800000u) - 1.0f;
  float x = fmaxf(lo, f * 2.0f + lo);
  float w = -logf((1.0f - x) * (1.0f + x));
  float p;
  if (w < 5.0f) {
    w -= 2.5f;
    p = 2.81022636e-08f;
    p = fmaf(p, w, 3.43273939e-07f);
    p = fmaf(p, w, -3.5233877e-06f);
    p = fmaf(p, w, -4.39150654e-06f);
    p = fmaf(p, w, 0.00021858087f);
    p = fmaf(p, w, -0.00125372503f);
    p = fmaf(p, w, -0.00417768164f);
    p = fmaf(p, w, 0.246640727f);
    p = fmaf(p, w, 1.50140941f);
  } else {
    w = sqrtf(w) - 3.0f;
    p = -0.000200214257f;
    p = fmaf(p, w, 0.000100950558f);
    p = fmaf(p, w, 0.00134934322f);
    p = fmaf(p, w, -0.00367342844f);
    p = fmaf(p, w, 0.00573950773f);
    p = fmaf(p, w, -0.0076224613f);
    p = fmaf(p, w, 0.00943887047f);
    p = fmaf(p, w, 1.00167406f);
    p = fmaf(p, w, 2.83297682f);
  }
  return 1.41421356f * p * x;
}

// ---------------- S1: pack weights (transpose + f32->bf16) ----------------
__global__ __launch_bounds__(256) void s1_pack(
    const float* __restrict__ W1f, const float* __restrict__ W1g,
    const float* __restrict__ W2f, const float* __restrict__ W2g,
    u16* __restrict__ W1fT, u16* __restrict__ W1gT,
    u16* __restrict__ W2fT, u16* __restrict__ W2gT) {
  __shared__ float tile[64][65];
  const int z = blockIdx.z;
  const float* in = (z == 0) ? W1f : (z == 1) ? W1g : (z == 2) ? W2f : W2g;
  u16* out = (z == 0) ? W1fT : (z == 1) ? W1gT : (z == 2) ? W2fT : W2gT;
  const int R = (z < 2) ? 4096 : 1024;
  const int C = (z < 2) ? 1024 : 4096;
  const int rt = (z < 2) ? blockIdx.x : blockIdx.y;
  const int ct = (z < 2) ? blockIdx.y : blockIdx.x;
  const int r0 = rt * 64, c0 = ct * 64;
  const int tix = threadIdx.x;
  #pragma unroll
  for (int i = 0; i < 16; ++i) {
    int lin = i * 256 + tix;
    int row = lin >> 6, col = lin & 63;
    tile[row][col] = in[(size_t)(r0 + row) * C + c0 + col];
  }
  __syncthreads();
  #pragma unroll
  for (int i = 0; i < 16; ++i) {
    int lin = i * 256 + tix;
    int orow = lin >> 6, ocol = lin & 63;
    out[(size_t)(c0 + orow) * R + r0 + ocol] = f2bf(tile[ocol][orow]);
  }
}

// ---------------- S2: init state, t=0 output, step keys ----------------
__global__ __launch_bounds__(256) void s2_init(
    const float* __restrict__ A0, float* __restrict__ A, u16* __restrict__ Abf,
    float* __restrict__ out, uint2* __restrict__ keys) {
  const int bid = blockIdx.x, tix = threadIdx.x;
  if (bid == 1024) {
    if (tix < 63) {
      u32 y0, y1;
      threefry2x32(0u, 42u, 0u, (u32)tix, y0, y1);
      keys[tix] = make_uint2(y0, y1);
    }
    return;
  }
  const int e = bid * 256 + tix;
  const int b = e >> 12, n = e & 4095;
  const float a0 = A0[e];
  const float sig = (n % 65 == 0) ? 0.0f : 1.0f / (1.0f + expf(-a0));
  const u16 ab = f2bf(a0);
  #pragma unroll
  for (int s = 0; s < 4; ++s) {
    size_t m = (size_t)s * 64 + b;
    A[m * 4096 + n] = a0;
    Abf[m * 4096 + n] = ab;
    out[((size_t)s * 4096 + b) * 4096 + n] = sig;
  }
}

// ---------------- G1: H = tanh(A @ W1 + b1 + t*w1_last) + dW gen ----------------
// grid 256 = 4 mt(64 rows) x 64 nt(32 cols over f|g 2048). 256 thr = 4 waves:
// (wm 0/32) x (kc 0/1 K-split). Ring-4 LDS, global_load_lds, 1 barrier/iter.
__global__ __launch_bounds__(256) void g1_hidden(
    const u16* __restrict__ Abf, const u16* __restrict__ W1fT, const u16* __restrict__ W1gT,
    u16* __restrict__ Hf, u16* __restrict__ Hg,
    const float* __restrict__ b1f, const float* __restrict__ b1g,
    const float* __restrict__ W1fv, const float* __restrict__ W1gv,
    const float* __restrict__ tarr, const uint2* __restrict__ keys,
    float* __restrict__ dWbuf, int step) {
  const int bid = blockIdx.x;
  const int nt = bid & 63;            // bid%8 == nt%8 -> W-panel sharers co-XCD
  const int mt = bid >> 6;
  const int fg = nt >> 5;
  const int n0 = (nt & 31) * 32;
  const int m0 = mt * 64;
  const u16* __restrict__ W = fg ? W1gT : W1fT;

  __shared__ __align__(16) u16 lA[4][4096];   // 8KB/buf: 64 rows x 128B
  __shared__ __align__(16) u16 lB[4][2048];   // 4KB/buf: 32 rows x 128B

  const int tix = threadIdx.x;
  const int wid = tix >> 6, lane = tix & 63;
  const int lr = lane & 15, kg = lane >> 4;
  const int kc = wid & 1;
  const int wm = (wid >> 1) * 32;

  auto stage = [&](int kidx) {
    const int b = kidx & 3;
    const int kb = kidx * 64;
    #pragma unroll
    for (int c = 0; c < 2; ++c) {
      const int l = c * 256 + tix;
      const int row = l >> 3, s = l & 7;
      gl_lds16(Abf + (size_t)(m0 + row) * 4096 + kb + ((s ^ (row & 7)) << 3),
               &lA[b][l * 8]);
    }
    {
      const int row = tix >> 3, s = tix & 7;
      gl_lds16(W + (size_t)(n0 + row) * 4096 + kb + ((s ^ (row & 7)) << 3),
               &lB[b][tix * 8]);
    }
  };
  stage(0); stage(1); stage(2);

  // dW for this step (4 normals/thread), overlaps prologue load latency
  {
    const uint2 key = keys[step];
    const float sdt = sqrtf(tarr[1] - tarr[0]);
    const u32 e0 = ((u32)bid * 256u + (u32)tix) * 4u;
    f32x4 v;
    #pragma unroll
    for (int j = 0; j < 4; ++j) {
      u32 y0, y1;
      threefry2x32(key.x, key.y, 0u, e0 + (u32)j, y0, y1);
      v[j] = bits_to_normal(y0 ^ y1) * sdt;
    }
    *(f32x4*)(dWbuf + e0) = v;
  }

  f32x4 z4 = {0.f, 0.f, 0.f, 0.f};
  f32x4 acc[2][2] = {{z4, z4}, {z4, z4}};
  const u32 kbyte = (u32)(kc * 64 + kg * 16);

  for (int it = 0; it < 64; ++it) {
    if (it < 62)       asm volatile("s_waitcnt vmcnt(6)" ::: "memory");
    else if (it == 62) asm volatile("s_waitcnt vmcnt(3)" ::: "memory");
    else               asm volatile("s_waitcnt vmcnt(0)" ::: "memory");
    __builtin_amdgcn_s_barrier();
    asm volatile("" ::: "memory");
    if (it + 3 < 64) stage(it + 3);
    const int b = it & 3;
    const char* cA = (const char*)lA[b];
    const char* cB = (const char*)lB[b];
    int r0i = wm + lr;
    bf16x8 a0 = *(const bf16x8*)(cA + r0i * 128 + (int)(kbyte ^ ((u32)(r0i & 7) << 4)));
    int r1i = wm + 16 + lr;
    bf16x8 a1 = *(const bf16x8*)(cA + r1i * 128 + (int)(kbyte ^ ((u32)(r1i & 7) << 4)));
    int r2i = lr;
    bf16x8 b0 = *(const bf16x8*)(cB + r2i * 128 + (int)(kbyte ^ ((u32)(r2i & 7) << 4)));
    int r3i = 16 + lr;
    bf16x8 b1 = *(const bf16x8*)(cB + r3i * 128 + (int)(kbyte ^ ((u32)(r3i & 7) << 4)));
    acc[0][0] = __builtin_amdgcn_mfma_f32_16x16x32_bf16(a0, b0, acc[0][0], 0, 0, 0);
    acc[0][1] = __builtin_amdgcn_mfma_f32_16x16x32_bf16(a0, b1, acc[0][1], 0, 0, 0);
    acc[1][0] = __builtin_amdgcn_mfma_f32_16x16x32_bf16(a1, b0, acc[1][0], 0, 0, 0);
    acc[1][1] = __builtin_amdgcn_mfma_f32_16x16x32_bf16(a1, b1, acc[1][1], 0, 0, 0);
  }

  // K-split partial-sum exchange with partner wave (wid^1); static acc indices
  f32x4 give0 = kc ? acc[0][0] : acc[1][0];
  f32x4 give1 = kc ? acc[0][1] : acc[1][1];
  f32x4 keep0 = kc ? acc[1][0] : acc[0][0];
  f32x4 keep1 = kc ? acc[1][1] : acc[0][1];
  __syncthreads();
  float* ex = (float*)&lA[0][0];
  *(f32x4*)(ex + wid * 512 + lane * 8)     = give0;
  *(f32x4*)(ex + wid * 512 + lane * 8 + 4) = give1;
  __syncthreads();
  f32x4 s0 = keep0 + *(const f32x4*)(ex + (wid ^ 1) * 512 + lane * 8);
  f32x4 s1 = keep1 + *(const f32x4*)(ex + (wid ^ 1) * 512 + lane * 8 + 4);

  const float tprev = tarr[step];
  const float* __restrict__ b1v = fg ? b1g : b1f;
  const float* __restrict__ wl = (fg ? W1gv : W1fv) + (size_t)4096 * 1024;
  u16* __restrict__ H = fg ? Hg : Hf;
  const int nc0 = n0 + lr, nc1 = n0 + 16 + lr;
  const float c0 = b1v[nc0] + tprev * wl[nc0];
  const float c1 = b1v[nc1] + tprev * wl[nc1];
  const int mB = m0 + wm + kc * 16 + kg * 4;
  #pragma unroll
  for (int r = 0; r < 4; ++r) {
    H[(size_t)(mB + r) * 1024 + nc0] = f2bf(tanhf(s0[r] + c0));
    H[(size_t)(mB + r) * 1024 + nc1] = f2bf(tanhf(s1[r] + c1));
  }
}

// ---------------- G2: drift/diff GEMMs + SDE update + output ----------------
// grid 256 = 4 mt(64) x 64 nt(64). 4 waves 2x2, wave 32x32. Ring-3, two passes
// (f: it 0..15, g: 16..31) share the ring seamlessly.
__global__ __launch_bounds__(256) void g2_update(
    const u16* __restrict__ Hf, const u16* __restrict__ Hg,
    const u16* __restrict__ W2fT, const u16* __restrict__ W2gT,
    const float* __restrict__ b2f, const float* __restrict__ b2g,
    float* __restrict__ A, u16* __restrict__ Abf,
    const float* __restrict__ dWbuf, float* __restrict__ out,
    const float* __restrict__ tarr, int step) {
  const int bid = blockIdx.x;
  const int nt = bid & 63, mt = bid >> 6;
  const int n0 = nt * 64, m0 = mt * 64;
  __shared__ __align__(16) u16 lA[3][4096];   // 8KB/buf
  __shared__ __align__(16) u16 lB[3][4096];   // 8KB/buf
  const int tix = threadIdx.x;
  const int wid = tix >> 6, lane = tix & 63;
  const int lr = lane & 15, kg = lane >> 4;
  const int wm = (wid >> 1) * 32, wn = (wid & 1) * 32;

  auto stage = [&](int kidx, int sb) {
    const u16* __restrict__ HA = (kidx < 16) ? Hf : Hg;
    const u16* __restrict__ WB = (kidx < 16) ? W2fT : W2gT;
    const int kb = (kidx & 15) * 64;
    #pragma unroll
    for (int c = 0; c < 2; ++c) {
      const int l = c * 256 + tix;
      const int row = l >> 3, s = l & 7;
      gl_lds16(HA + (size_t)(m0 + row) * 1024 + kb + ((s ^ (row & 7)) << 3),
               &lA[sb][l * 8]);
      gl_lds16(WB + (size_t)(n0 + row) * 1024 + kb + ((s ^ (row & 7)) << 3),
               &lB[sb][l * 8]);
    }
  };
  stage(0, 0); stage(1, 1);

  f32x4 z4 = {0.f, 0.f, 0.f, 0.f};
  f32x4 aF[2][2] = {{z4, z4}, {z4, z4}};
  f32x4 aG[2][2] = {{z4, z4}, {z4, z4}};
  int cb = 0;

#define G2_BODY(ACC, it)                                                        \
  {                                                                             \
    if ((it) < 31) asm volatile("s_waitcnt vmcnt(4)" ::: "memory");             \
    else           asm volatile("s_waitcnt vmcnt(0)" ::: "memory");             \
    __builtin_amdgcn_s_barrier();                                               \
    asm volatile("" ::: "memory");                                              \
    if ((it) + 2 < 32) { int sb = cb - 1; if (sb < 0) sb = 2; stage((it) + 2, sb); } \
    const char* cA = (const char*)lA[cb];                                       \
    const char* cB = (const char*)lB[cb];                                       \
    _Pragma("unroll")                                                           \
    for (int kcc = 0; kcc < 2; ++kcc) {                                         \
      const u32 kbyte = (u32)(kcc * 64 + kg * 16);                              \
      int ra0 = wm + lr;                                                        \
      bf16x8 a0 = *(const bf16x8*)(cA + ra0 * 128 + (int)(kbyte ^ ((u32)(ra0 & 7) << 4))); \
      int ra1 = wm + 16 + lr;                                                   \
      bf16x8 a1 = *(const bf16x8*)(cA + ra1 * 128 + (int)(kbyte ^ ((u32)(ra1 & 7) << 4))); \
      int rb0 = wn + lr;                                                        \
      bf16x8 b0 = *(const bf16x8*)(cB + rb0 * 128 + (int)(kbyte ^ ((u32)(rb0 & 7) << 4))); \
      int rb1 = wn + 16 + lr;                                                   \
      bf16x8 b1 = *(const bf16x8*)(cB + rb1 * 128 + (int)(kbyte ^ ((u32)(rb1 & 7) << 4))); \
      ACC[0][0] = __builtin_amdgcn_mfma_f32_16x16x32_bf16(a0, b0, ACC[0][0], 0, 0, 0); \
      ACC[0][1] = __builtin_amdgcn_mfma_f32_16x16x32_bf16(a0, b1, ACC[0][1], 0, 0, 0); \
      ACC[1][0] = __builtin_amdgcn_mfma_f32_16x16x32_bf16(a1, b0, ACC[1][0], 0, 0, 0); \
      ACC[1][1] = __builtin_amdgcn_mfma_f32_16x16x32_bf16(a1, b1, ACC[1][1], 0, 0, 0); \
    }                                                                           \
    cb = (cb == 2) ? 0 : cb + 1;                                                \
  }

  for (int it = 0; it < 16; ++it) G2_BODY(aF, it);
  for (int it = 16; it < 32; ++it) G2_BODY(aG, it);
#undef G2_BODY

  const float dt = tarr[1] - tarr[0];
  #pragma unroll
  for (int i = 0; i < 2; ++i) {
    #pragma unroll
    for (int j = 0; j < 2; ++j) {
      const f32x4 df = aF[i][j], dg = aG[i][j];
      const int mb = m0 + wm + i * 16 + kg * 4;
      const int nc = n0 + wn + j * 16 + lr;
      const float bfv = b2f[nc], bgv = b2g[nc];
      #pragma unroll
      for (int r = 0; r < 4; ++r) {
        const int m = mb + r;
        const float drift = df[r] + bfv;
        const float graw = dg[r] + bgv;
        const float diff = fmaxf(graw, 0.0f) + log1pf(expf(-fabsf(graw)));
        const size_t ai = (size_t)m * 4096 + nc;
        const float aprev = A[ai];
        const float dw = dWbuf[(size_t)(m & 63) * 4096 + nc];
        const float anew = aprev + drift * dt + diff * dw;
        A[ai] = anew;
        Abf[ai] = f2bf(anew);
        const float sig = (nc % 65 == 0) ? 0.0f : 1.0f / (1.0f + expf(-anew));
        out[((size_t)((m >> 6) * 64 + step + 1) * 64 + (m & 63)) * 4096 + nc] = sig;
      }
    }
  }
}

// ---------------- launch ----------------
extern "C" void kernel_launch(void* const* d_in, const int* in_sizes, int n_in,
                              void* d_out, int out_size, void* d_ws, size_t ws_size,
                              hipStream_t stream) {
  const float* A0 = (const float*)d_in[0];
  const float* tarr = (const float*)d_in[1];
  const float* W1f = (const float*)d_in[2];
  const float* b1f = (const float*)d_in[3];
  const float* W2f = (const float*)d_in[4];
  const float* b2f = (const float*)d_in[5];
  const float* W1g = (const float*)d_in[6];
  const float* b1g = (const float*)d_in[7];
  const float* W2g = (const float*)d_in[8];
  const float* b2g = (const float*)d_in[9];
  float* out = (float*)d_out;
  char* ws = (char*)d_ws;
  const size_t MB = 1024 * 1024;
  u16* W1fT = (u16*)(ws + 0 * MB);
  u16* W1gT = (u16*)(ws + 8 * MB);
  u16* W2fT = (u16*)(ws + 16 * MB);
  u16* W2gT = (u16*)(ws + 24 * MB);
  float* A  = (float*)(ws + 32 * MB);
  u16* Abf  = (u16*)(ws + 36 * MB);
  u16* Hf   = (u16*)(ws + 38 * MB);
  u16* Hg   = (u16*)(ws + 38 * MB + 512 * 1024);
  float* dW = (float*)(ws + 39 * MB);
  uint2* keys = (uint2*)(ws + 40 * MB);

  s1_pack<<<dim3(64, 16, 4), 256, 0, stream>>>(W1f, W1g, W2f, W2g, W1fT, W1gT, W2fT, W2gT);
  s2_init<<<dim3(1025), 256, 0, stream>>>(A0, A, Abf, out, keys);
  for (int i = 0; i < 63; ++i) {
    g1_hidden<<<dim3(256), 256, 0, stream>>>(Abf, W1fT, W1gT, Hf, Hg, b1f, b1g,
                                             W1f, W1g, tarr, keys, dW, i);
    g2_update<<<dim3(256), 256, 0, stream>>>(Hf, Hg, W2fT, W2gT, b2f, b2g,
                                             A, Abf, dW, out, tarr, i);
  }
}

// Round 4
// 2681.336 us; speedup vs baseline: 1.4550x; 1.4550x over previous
//
#include <hip/hip_runtime.h>
#include <cstdint>

using u16 = unsigned short;
using u32 = uint32_t;

typedef __bf16 bf16x8 __attribute__((ext_vector_type(8)));
typedef float  f32x4  __attribute__((ext_vector_type(4)));
typedef u32    uvec4  __attribute__((ext_vector_type(4)));

#define MFMA(a, b, c) __builtin_amdgcn_mfma_f32_16x16x32_bf16((a), (b), (c), 0, 0, 0)

// ---------------- numeric helpers ----------------
static __device__ __forceinline__ u16 f2bf(float x) {
  u32 u = __float_as_uint(x);
  u32 r = (u + 0x7FFFu + ((u >> 16) & 1u)) >> 16;   // RNE
  return (u16)r;
}

static __device__ __forceinline__ u32 rotl32(u32 v, int s) {
  return (v << s) | (v >> (32 - s));
}

// JAX threefry2x32 (20 rounds)
static __device__ __forceinline__ void threefry2x32(u32 k0, u32 k1, u32 x0, u32 x1,
                                                    u32& o0, u32& o1) {
  u32 k2 = k0 ^ k1 ^ 0x1BD11BDAu;
  x0 += k0; x1 += k1;
  x0 += x1; x1 = rotl32(x1, 13); x1 ^= x0;
  x0 += x1; x1 = rotl32(x1, 15); x1 ^= x0;
  x0 += x1; x1 = rotl32(x1, 26); x1 ^= x0;
  x0 += x1; x1 = rotl32(x1, 6);  x1 ^= x0;
  x0 += k1; x1 += k2 + 1u;
  x0 += x1; x1 = rotl32(x1, 17); x1 ^= x0;
  x0 += x1; x1 = rotl32(x1, 29); x1 ^= x0;
  x0 += x1; x1 = rotl32(x1, 16); x1 ^= x0;
  x0 += x1; x1 = rotl32(x1, 24); x1 ^= x0;
  x0 += k2; x1 += k0 + 2u;
  x0 += x1; x1 = rotl32(x1, 13); x1 ^= x0;
  x0 += x1; x1 = rotl32(x1, 15); x1 ^= x0;
  x0 += x1; x1 = rotl32(x1, 26); x1 ^= x0;
  x0 += x1; x1 = rotl32(x1, 6);  x1 ^= x0;
  x0 += k0; x1 += k1 + 3u;
  x0 += x1; x1 = rotl32(x1, 17); x1 ^= x0;
  x0 += x1; x1 = rotl32(x1, 29); x1 ^= x0;
  x0 += x1; x1 = rotl32(x1, 16); x1 ^= x0;
  x0 += x1; x1 = rotl32(x1, 24); x1 ^= x0;
  x0 += k1; x1 += k2 + 4u;
  x0 += x1; x1 = rotl32(x1, 13); x1 ^= x0;
  x0 += x1; x1 = rotl32(x1, 15); x1 ^= x0;
  x0 += x1; x1 = rotl32(x1, 26); x1 ^= x0;
  x0 += x1; x1 = rotl32(x1, 6);  x1 ^= x0;
  x0 += k2; x1 += k0 + 5u;
  o0 = x0; o1 = x1;
}

// bits -> N(0,1) exactly like jax.random.normal(f32)
static __device__ __forceinline__ float bits_to_normal(u32 bits) {
  const float lo = __uint_as_float(0xBF7FFFFFu);
  float f = __uint_as_float((bits >> 9) | 0x3F800000u) - 1.0f;
  float x = fmaxf(lo, f * 2.0f + lo);
  float w = -logf((1.0f - x) * (1.0f + x));
  float p;
  if (w < 5.0f) {
    w -= 2.5f;
    p = 2.81022636e-08f;
    p = fmaf(p, w, 3.43273939e-07f);
    p = fmaf(p, w, -3.5233877e-06f);
    p = fmaf(p, w, -4.39150654e-06f);
    p = fmaf(p, w, 0.00021858087f);
    p = fmaf(p, w, -0.00125372503f);
    p = fmaf(p, w, -0.00417768164f);
    p = fmaf(p, w, 0.246640727f);
    p = fmaf(p, w, 1.50140941f);
  } else {
    w = sqrtf(w) - 3.0f;
    p = -0.000200214257f;
    p = fmaf(p, w, 0.000100950558f);
    p = fmaf(p, w, 0.00134934322f);
    p = fmaf(p, w, -0.00367342844f);
    p = fmaf(p, w, 0.00573950773f);
    p = fmaf(p, w, -0.0076224613f);
    p = fmaf(p, w, 0.00943887047f);
    p = fmaf(p, w, 1.00167406f);
    p = fmaf(p, w, 2.83297682f);
  }
  return 1.41421356f * p * x;
}

// ---------------- S1: pack weights (transpose + f32->bf16) ----------------
__global__ __launch_bounds__(256) void s1_pack(
    const float* __restrict__ W1f, const float* __restrict__ W1g,
    const float* __restrict__ W2f, const float* __restrict__ W2g,
    u16* __restrict__ W1fT, u16* __restrict__ W1gT,
    u16* __restrict__ W2fT, u16* __restrict__ W2gT) {
  __shared__ float tile[64][65];
  const int z = blockIdx.z;
  const float* in = (z == 0) ? W1f : (z == 1) ? W1g : (z == 2) ? W2f : W2g;
  u16* out = (z == 0) ? W1fT : (z == 1) ? W1gT : (z == 2) ? W2fT : W2gT;
  const int R = (z < 2) ? 4096 : 1024;
  const int C = (z < 2) ? 1024 : 4096;
  const int rt = (z < 2) ? blockIdx.x : blockIdx.y;
  const int ct = (z < 2) ? blockIdx.y : blockIdx.x;
  const int r0 = rt * 64, c0 = ct * 64;
  const int tix = threadIdx.x;
  #pragma unroll
  for (int i = 0; i < 16; ++i) {
    int lin = i * 256 + tix;
    int row = lin >> 6, col = lin & 63;
    tile[row][col] = in[(size_t)(r0 + row) * C + c0 + col];
  }
  __syncthreads();
  #pragma unroll
  for (int i = 0; i < 16; ++i) {
    int lin = i * 256 + tix;
    int orow = lin >> 6, ocol = lin & 63;
    out[(size_t)(c0 + orow) * R + r0 + ocol] = f2bf(tile[ocol][orow]);
  }
}

// ---------------- S2: init state + t=0 output ----------------
__global__ __launch_bounds__(256) void s2_init(
    const float* __restrict__ A0, float* __restrict__ A, u16* __restrict__ Abf,
    float* __restrict__ out) {
  const int bid = blockIdx.x, tix = threadIdx.x;
  const int e = bid * 256 + tix;
  const int b = e >> 12, n = e & 4095;
  const float a0 = A0[e];
  const float sig = (n % 65 == 0) ? 0.0f : 1.0f / (1.0f + expf(-a0));
  const u16 ab = f2bf(a0);
  #pragma unroll
  for (int s = 0; s < 4; ++s) {
    size_t m = (size_t)s * 64 + b;
    A[m * 4096 + n] = a0;
    Abf[m * 4096 + n] = ab;
    out[((size_t)s * 4096 + b) * 4096 + n] = sig;
  }
}

// ---------------- dW generation (partitionable threefry, one step each) ----------------
// step<0: pregen all -> grid 63*32, step = bid>>5, sub = bid&31
// step>=0: fallback single step -> grid 32, sub = bid
__global__ __launch_bounds__(256) void dw_gen(
    const float* __restrict__ tarr, float* __restrict__ dst_base, int step_param) {
  const int bid = blockIdx.x, tix = threadIdx.x;
  const int step = (step_param < 0) ? (bid >> 5) : step_param;
  const int sub = (step_param < 0) ? (bid & 31) : bid;
  u32 k0, k1;
  threefry2x32(0u, 42u, 0u, (u32)step, k0, k1);   // split(key(42),63)[step]
  const float sdt = sqrtf(tarr[1] - tarr[0]);
  float* dst = dst_base + ((step_param < 0) ? (size_t)step * 262144 : 0);
  #pragma unroll
  for (int j = 0; j < 32; ++j) {
    u32 e = (u32)(sub * 8192 + j * 256 + tix);
    u32 y0, y1;
    threefry2x32(k0, k1, 0u, e, y0, y1);
    dst[e] = bits_to_normal(y0 ^ y1) * sdt;
  }
}

// ---------------- G1: H = tanh(A @ W1 + b1 + t*w1_last) ----------------
// grid 256 = 4mt(64 rows) x 2fg x 32nt(32 cols). 512 thr = 8 waves (4 wm x 2 wn),
// wave computes one 16x16 fragment over K=4096. 2-barrier reg-prefetch loop.
__global__ __launch_bounds__(512) void g1_hidden(
    const u16* __restrict__ Abf, const u16* __restrict__ W1fT, const u16* __restrict__ W1gT,
    u16* __restrict__ Hf, u16* __restrict__ Hg,
    const float* __restrict__ b1f, const float* __restrict__ b1g,
    const float* __restrict__ W1fv, const float* __restrict__ W1gv,
    const float* __restrict__ tarr, int step) {
  const int bid = blockIdx.x;
  const int nt = bid & 31, fg = (bid >> 5) & 1, mt = bid >> 6;
  const int m0 = mt * 64, n0 = nt * 32;
  const u16* __restrict__ W = fg ? W1gT : W1fT;
  __shared__ __align__(16) u16 lA[2][64 * 64];   // 8KB each
  __shared__ __align__(16) u16 lB[2][32 * 64];   // 4KB each
  const int tix = threadIdx.x;
  const int wid = tix >> 6, lane = tix & 63;
  const int lr = lane & 15, kg = lane >> 4;
  const int wm = (wid >> 1) * 16, wn = (wid & 1) * 16;

  const int arow = tix >> 3, asc = tix & 7;
  const u32 awr = (u32)arow * 128 + (u32)((asc * 16) ^ ((arow & 7) << 4));
  const u16* gA = Abf + (size_t)(m0 + arow) * 4096 + asc * 8;
  const u16* gB = W + (size_t)(n0 + arow) * 4096 + asc * 8;   // valid for tix<256

  const int ar = wm + lr, br = wn + lr;
  const u32 abyte = (u32)ar * 128 + (u32)((kg * 16) ^ ((ar & 7) << 4));
  const u32 bbyte = (u32)br * 128 + (u32)((kg * 16) ^ ((br & 7) << 4));

  uvec4 ra = *(const uvec4*)gA;
  uvec4 rb = {0, 0, 0, 0};
  if (tix < 256) rb = *(const uvec4*)gB;
  f32x4 acc = {0.f, 0.f, 0.f, 0.f};

  for (int it = 0; it < 64; ++it) {
    const int b = it & 1;
    __syncthreads();
    *(uvec4*)((char*)lA[b] + awr) = ra;
    if (tix < 256) *(uvec4*)((char*)lB[b] + awr) = rb;
    if (it + 1 < 64) {
      gA += 64;
      ra = *(const uvec4*)gA;
      if (tix < 256) { gB += 64; rb = *(const uvec4*)gB; }
    }
    __syncthreads();
    bf16x8 a0 = *(const bf16x8*)((char*)lA[b] + abyte);
    bf16x8 b0 = *(const bf16x8*)((char*)lB[b] + bbyte);
    acc = MFMA(a0, b0, acc);
    bf16x8 a1 = *(const bf16x8*)((char*)lA[b] + (abyte ^ 64u));
    bf16x8 b1 = *(const bf16x8*)((char*)lB[b] + (bbyte ^ 64u));
    acc = MFMA(a1, b1, acc);
  }

  const float tprev = tarr[step];
  const float* __restrict__ b1v = fg ? b1g : b1f;
  const float* __restrict__ wl = (fg ? W1gv : W1fv) + (size_t)4096 * 1024;
  u16* __restrict__ H = fg ? Hg : Hf;
  const int nc = n0 + wn + lr;
  const float c = b1v[nc] + tprev * wl[nc];
  const int mB = m0 + wm + kg * 4;
  #pragma unroll
  for (int r = 0; r < 4; ++r)
    H[(size_t)(mB + r) * 1024 + nc] = f2bf(tanhf(acc[r] + c));
}

// ---------------- G2: drift/diff GEMMs + SDE update + output ----------------
// grid 256 = 4mt(64) x 64nt(64). 512 thr = 8 waves (4 wm x 2 wn), wave 16x32.
static __device__ __forceinline__ void g2_pass(
    const u16* __restrict__ HA, const u16* __restrict__ WB,
    int m0, int n0, int tix,
    u16 (* __restrict__ lA)[4096], u16 (* __restrict__ lB)[4096],
    u32 awr, u32 abyte, u32 bbyte0, u32 bbyte1,
    f32x4& acc0, f32x4& acc1) {
  const int arow = tix >> 3, asc = tix & 7;
  const u16* gA = HA + (size_t)(m0 + arow) * 1024 + asc * 8;
  const u16* gB = WB + (size_t)(n0 + arow) * 1024 + asc * 8;
  uvec4 ra = *(const uvec4*)gA;
  uvec4 rb = *(const uvec4*)gB;
  for (int it = 0; it < 16; ++it) {
    const int b = it & 1;
    __syncthreads();
    *(uvec4*)((char*)lA[b] + awr) = ra;
    *(uvec4*)((char*)lB[b] + awr) = rb;
    if (it + 1 < 16) {
      gA += 64; gB += 64;
      ra = *(const uvec4*)gA;
      rb = *(const uvec4*)gB;
    }
    __syncthreads();
    bf16x8 a0 = *(const bf16x8*)((char*)lA[b] + abyte);
    bf16x8 b0 = *(const bf16x8*)((char*)lB[b] + bbyte0);
    bf16x8 b1 = *(const bf16x8*)((char*)lB[b] + bbyte1);
    acc0 = MFMA(a0, b0, acc0);
    acc1 = MFMA(a0, b1, acc1);
    bf16x8 a1 = *(const bf16x8*)((char*)lA[b] + (abyte ^ 64u));
    bf16x8 b2 = *(const bf16x8*)((char*)lB[b] + (bbyte0 ^ 64u));
    bf16x8 b3 = *(const bf16x8*)((char*)lB[b] + (bbyte1 ^ 64u));
    acc0 = MFMA(a1, b2, acc0);
    acc1 = MFMA(a1, b3, acc1);
  }
}

__global__ __launch_bounds__(512) void g2_update(
    const u16* __restrict__ Hf, const u16* __restrict__ Hg,
    const u16* __restrict__ W2fT, const u16* __restrict__ W2gT,
    const float* __restrict__ b2f, const float* __restrict__ b2g,
    float* __restrict__ A, u16* __restrict__ Abf,
    const float* __restrict__ dWstep, float* __restrict__ out,
    const float* __restrict__ tarr, int step) {
  const int bid = blockIdx.x;
  const int nt = bid & 63, mt = bid >> 6;
  const int n0 = nt * 64, m0 = mt * 64;
  __shared__ __align__(16) u16 lA[2][64 * 64];
  __shared__ __align__(16) u16 lB[2][64 * 64];
  const int tix = threadIdx.x;
  const int wid = tix >> 6, lane = tix & 63;
  const int lr = lane & 15, kg = lane >> 4;
  const int wm = (wid >> 1) * 16, wn = (wid & 1) * 32;

  const int arow = tix >> 3, asc = tix & 7;
  const u32 awr = (u32)arow * 128 + (u32)((asc * 16) ^ ((arow & 7) << 4));
  const int ar = wm + lr, br0 = wn + lr, br1 = wn + 16 + lr;
  const u32 abyte = (u32)ar * 128 + (u32)((kg * 16) ^ ((ar & 7) << 4));
  const u32 bbyte0 = (u32)br0 * 128 + (u32)((kg * 16) ^ ((br0 & 7) << 4));
  const u32 bbyte1 = (u32)br1 * 128 + (u32)((kg * 16) ^ ((br1 & 7) << 4));

  f32x4 z4 = {0.f, 0.f, 0.f, 0.f};
  f32x4 aF0 = z4, aF1 = z4, aG0 = z4, aG1 = z4;
  g2_pass(Hf, W2fT, m0, n0, tix, lA, lB, awr, abyte, bbyte0, bbyte1, aF0, aF1);
  g2_pass(Hg, W2gT, m0, n0, tix, lA, lB, awr, abyte, bbyte0, bbyte1, aG0, aG1);

  const float dt = tarr[1] - tarr[0];
  const int mB = m0 + wm + kg * 4;
  #pragma unroll
  for (int j = 0; j < 2; ++j) {
    const f32x4 df = j ? aF1 : aF0;
    const f32x4 dg = j ? aG1 : aG0;
    const int nc = n0 + wn + j * 16 + lr;
    const float bfv = b2f[nc], bgv = b2g[nc];
    #pragma unroll
    for (int r = 0; r < 4; ++r) {
      const int m = mB + r;
      const float drift = df[r] + bfv;
      const float graw = dg[r] + bgv;
      const float diff = fmaxf(graw, 0.0f) + log1pf(expf(-fabsf(graw)));
      const size_t ai = (size_t)m * 4096 + nc;
      const float aprev = A[ai];
      const float dw = dWstep[(size_t)(m & 63) * 4096 + nc];
      const float anew = aprev + drift * dt + diff * dw;
      A[ai] = anew;
      Abf[ai] = f2bf(anew);
      const float sig = (nc % 65 == 0) ? 0.0f : 1.0f / (1.0f + expf(-anew));
      out[((size_t)((m >> 6) * 64 + step + 1) * 64 + (m & 63)) * 4096 + nc] = sig;
    }
  }
}

// ---------------- launch ----------------
extern "C" void kernel_launch(void* const* d_in, const int* in_sizes, int n_in,
                              void* d_out, int out_size, void* d_ws, size_t ws_size,
                              hipStream_t stream) {
  const float* A0 = (const float*)d_in[0];
  const float* tarr = (const float*)d_in[1];
  const float* W1f = (const float*)d_in[2];
  const float* b1f = (const float*)d_in[3];
  const float* W2f = (const float*)d_in[4];
  const float* b2f = (const float*)d_in[5];
  const float* W1g = (const float*)d_in[6];
  const float* b1g = (const float*)d_in[7];
  const float* W2g = (const float*)d_in[8];
  const float* b2g = (const float*)d_in[9];
  float* out = (float*)d_out;
  char* ws = (char*)d_ws;
  const size_t MB = 1024 * 1024;
  u16* W1fT = (u16*)(ws + 0 * MB);
  u16* W1gT = (u16*)(ws + 8 * MB);
  u16* W2fT = (u16*)(ws + 16 * MB);
  u16* W2gT = (u16*)(ws + 24 * MB);
  float* A  = (float*)(ws + 32 * MB);
  u16* Abf  = (u16*)(ws + 36 * MB);
  u16* Hf   = (u16*)(ws + 38 * MB);
  u16* Hg   = (u16*)(ws + 38 * MB + 512 * 1024);
  float* dWfb = (float*)(ws + 39 * MB);        // fallback single-step buffer
  float* dWall = (float*)(ws + 40 * MB);       // 63 MB when available
  const bool pre = ws_size >= (size_t)104 * MB;

  s1_pack<<<dim3(64, 16, 4), 256, 0, stream>>>(W1f, W1g, W2f, W2g, W1fT, W1gT, W2fT, W2gT);
  s2_init<<<dim3(1024), 256, 0, stream>>>(A0, A, Abf, out);
  if (pre) dw_gen<<<dim3(63 * 32), 256, 0, stream>>>(tarr, dWall, -1);
  for (int i = 0; i < 63; ++i) {
    if (!pre) dw_gen<<<dim3(32), 256, 0, stream>>>(tarr, dWfb, i);
    g1_hidden<<<dim3(256), 512, 0, stream>>>(Abf, W1fT, W1gT, Hf, Hg, b1f, b1g,
                                             W1f, W1g, tarr, i);
    const float* dWstep = pre ? (dWall + (size_t)i * 262144) : dWfb;
    g2_update<<<dim3(256), 512, 0, stream>>>(Hf, Hg, W2fT, W2gT, b2f, b2g,
                                             A, Abf, dWstep, out, tarr, i);
  }
}